// Round 1
// baseline (117.723 us; speedup 1.0000x reference)
//
#include <hip/hip_runtime.h>
#include <hip/hip_bf16.h>

// SConv2dAvg: stride-2 conv with per-output-pixel stochastic tap selection.
// B=32 C=128 H=W=64, O=256 kh=kw=3, oh=ow=32, PAD=1, STRIDE=2.
// Implicit GEMM: A = weight [O x K], B = gathered patches [K x Mpix],
// K = C*9 ordered k = tap*128 + c  (tap = i*3+j fixed within each K-step of 64).
// mfma_f32_16x16x32_bf16, fp32 accumulate.

typedef short bf16x8 __attribute__((ext_vector_type(8)));
typedef float f32x4  __attribute__((ext_vector_type(4)));

#define KSTEPS 18
#define WPRE_BYTES (KSTEPS * 256 * 64 * 2)  // 589824

// round-to-nearest-even fp32 -> bf16 (bit twiddle; no NaN inputs here)
__device__ __forceinline__ unsigned short f2bf(float x) {
  unsigned u = __float_as_uint(x);
  return (unsigned short)((u + 0x7fffu + ((u >> 16) & 1u)) >> 16);
}
__device__ __forceinline__ unsigned pk2(float a, float b) {
  unsigned ua = __float_as_uint(a), ub = __float_as_uint(b);
  return ((ua + 0x7fffu + ((ua >> 16) & 1u)) >> 16) |
         ((ub + 0x7fffu + ((ub >> 16) & 1u)) & 0xffff0000u);
}
__device__ __forceinline__ bf16x8 ld_frag(const uint4* a) {
  union { uint4 u; bf16x8 s; } cv; cv.u = *a; return cv.s;
}
__device__ __forceinline__ void async16(const void* g, void* l) {
  __builtin_amdgcn_global_load_lds(
      (__attribute__((address_space(1))) void*)(void*)g,
      (__attribute__((address_space(3))) void*)l, 16, 0, 0);
}

// -------- pre-pass: weight fp32 [O][C][3][3] -> bf16 wpre[18][256][64] ------
// wpre[kk][o][k_in] = bf16( w[o, c, i, j] ) with
//   k_g = kk*64 + (k_in ^ ((o&7)<<3))   (LDS XOR swizzle pre-baked),
//   tap = k_g>>7, c = k_g&127, i = tap/3, j = tap%3.
__global__ __launch_bounds__(256) void wprep(const float* __restrict__ w,
                                             unsigned short* __restrict__ wpre) {
  int idx = (blockIdx.x << 8) + threadIdx.x;
  if (idx >= KSTEPS * 16384) return;
  int k_in = idx & 63;
  int o    = (idx >> 6) & 255;
  int kk   = idx >> 14;
  int kg   = (kk << 6) + (k_in ^ ((o & 7) << 3));
  int tap  = kg >> 7;
  int c    = kg & 127;
  int di   = (tap >= 6) ? 2 : ((tap >= 3) ? 1 : 0);
  int dj   = tap - di * 3;
  wpre[idx] = f2bf(w[(o * 128 + c) * 9 + di * 3 + dj]);
}

// ----------------------------- main kernel ---------------------------------
// grid = 256 blocks (32 b x 8 y-groups of 4 rows), block = 512 threads (8 waves).
// Tile: 256 o  x 128 pixels, K-step 64. LDS: patches 16KB + weight 32KB.
__global__ __launch_bounds__(512, 2) void sconv_mfma(
    const float* __restrict__ in,            // [32][128][64][64]
    const unsigned short* __restrict__ wpre, // [18][256][64] bf16, pre-swizzled
    const float* __restrict__ bias,          // [256]
    const int* __restrict__ selh,            // [32][32]
    const int* __restrict__ selw,            // [32][32]
    float* __restrict__ out)                 // [32][256][32][32]
{
  __shared__ uint4 Alds[128 * 8];   // patches [pix][8 slots of 8 bf16], swizzled
  __shared__ uint4 Blds[256 * 8];   // weight  [o][8 slots], linear dest (pre-swz in ws)
  __shared__ float bias_s[256];

  const int tid = threadIdx.x;
  const int blk = blockIdx.x;
  const int b   = blk >> 3;
  const int y0  = (blk & 7) << 2;

  if (tid < 256) bias_s[tid] = bias[tid];

  // gather role: thread owns pixel p (0..127) and a 16-channel slice csub
  const int p    = tid & 127;
  const int csub = tid >> 7;                  // 0..3
  const int py   = y0 + (p >> 5);
  const int px   = p & 31;
  const int rh0  = 2 * py + selh[(py << 5) | px] - 1;  // + di -> input row
  const int rw0  = 2 * px + selw[(py << 5) | px] - 1;  // + dj -> input col
  const float* inb = in + ((size_t)b << 19);  // b*128*64*64

  // MFMA role
  const int wv = tid >> 6;        // wave 0..7
  const int ln = tid & 63;
  const int wo = wv & 3;          // o-wave (4 x 64 o)
  const int wp = wv >> 2;         // pixel-wave (2 x 64 pix)
  const int lo = ln & 15;
  const int hi = ln >> 4;

  f32x4 acc[4][4] = {};           // [o-frag][pix-frag]

  for (int kk = 0; kk < KSTEPS; ++kk) {
    const int tap = kk >> 1;
    const int di  = (tap >= 6) ? 2 : ((tap >= 3) ? 1 : 0);
    const int dj  = tap - di * 3;
    const int rh  = rh0 + di;
    const int rw  = rw0 + dj;
    const bool ok = (rh >= 0) & (rh < 64) & (rw >= 0) & (rw < 64);

    // ---- stage weight K-step: 32KB linear global_load_lds (16B/lane) ----
    {
      const char* gbase = (const char*)wpre + ((size_t)kk << 15);
#pragma unroll
      for (int r = 0; r < 4; ++r) {
        int chunk = (wv << 2) + r;            // 0..31, 1KB each, wave-uniform
        async16(gbase + (chunk << 10) + (ln << 4), Blds + (chunk << 6));
      }
    }

    // ---- gather 16 channels for (pixel p, tap) and write swizzled bf16 ----
    {
      const float* src = inb + ((size_t)(((kk & 1) << 6) + (csub << 4)) << 12)
                             + (rh << 6) + rw;
      float v[16];
#pragma unroll
      for (int cc = 0; cc < 16; ++cc)
        v[cc] = ok ? src[(size_t)cc << 12] : 0.f;
#pragma unroll
      for (int z = 0; z < 2; ++z) {
        uint4 d;
        d.x = pk2(v[z * 8 + 0], v[z * 8 + 1]);
        d.y = pk2(v[z * 8 + 2], v[z * 8 + 3]);
        d.z = pk2(v[z * 8 + 4], v[z * 8 + 5]);
        d.w = pk2(v[z * 8 + 6], v[z * 8 + 7]);
        int slot = ((csub << 1) | z) ^ (p & 7);   // XOR swizzle (G4)
        Alds[(p << 3) + slot] = d;
      }
    }

    __syncthreads();   // drains vmcnt(0) (global_load_lds) + lgkmcnt

    // ---- fragment reads (swizzled ds_read_b128) + 32 MFMA ----
    bf16x8 FW[4][2], FP[4][2];
#pragma unroll
    for (int f = 0; f < 4; ++f) {
      const int orow = (wo << 6) + (f << 4) + lo;
      const int prow = (wp << 6) + (f << 4) + lo;
#pragma unroll
      for (int ks = 0; ks < 2; ++ks) {
        FW[f][ks] = ld_frag(Blds + (orow << 3) + (((ks << 2) | hi) ^ (orow & 7)));
        FP[f][ks] = ld_frag(Alds + (prow << 3) + (((ks << 2) | hi) ^ (prow & 7)));
      }
    }
#pragma unroll
    for (int fo = 0; fo < 4; ++fo)
#pragma unroll
      for (int fp = 0; fp < 4; ++fp)
#pragma unroll
        for (int ks = 0; ks < 2; ++ks)
          acc[fo][fp] = __builtin_amdgcn_mfma_f32_16x16x32_bf16(
              FW[fo][ks], FP[fp][ks], acc[fo][fp], 0, 0, 0);

    __syncthreads();   // reads done before next iteration overwrites LDS
  }

  // ---- epilogue: D[row=o: (hi<<2)+j][col=pix: lo], +bias, fp32 stores ----
  float* ob = out + ((size_t)b << 18) + (y0 << 5);
#pragma unroll
  for (int fo = 0; fo < 4; ++fo) {
    const int obase = (wo << 6) + (fo << 4) + (hi << 2);
#pragma unroll
    for (int fp = 0; fp < 4; ++fp) {
      const int pix = (wp << 6) + (fp << 4) + lo;
#pragma unroll
      for (int j = 0; j < 4; ++j) {
        const int o = obase + j;
        ob[((size_t)o << 10) + pix] = acc[fo][fp][j] + bias_s[o];
      }
    }
  }
}

// ------------------- exact fp32 fallback (ws too small) --------------------
__global__ __launch_bounds__(256) void sconv_naive(
    const float* __restrict__ in, const float* __restrict__ w,
    const float* __restrict__ bias, const int* __restrict__ selh,
    const int* __restrict__ selw, float* __restrict__ out) {
  int idx = (blockIdx.x << 8) + threadIdx.x;
  if (idx >= 32 * 256 * 32 * 32) return;
  int x = idx & 31, y = (idx >> 5) & 31, o = (idx >> 10) & 255, b = idx >> 18;
  int rh0 = 2 * y + selh[(y << 5) | x] - 1;
  int rw0 = 2 * x + selw[(y << 5) | x] - 1;
  const float* inb = in + ((size_t)b << 19);
  const float* wo_ = w + o * 1152;
  float acc = bias[o];
  for (int c = 0; c < 128; ++c)
    for (int i = 0; i < 3; ++i) {
      int rh = rh0 + i;
      if (rh < 0 || rh >= 64) continue;
      for (int j = 0; j < 3; ++j) {
        int rw = rw0 + j;
        if (rw < 0 || rw >= 64) continue;
        acc += inb[(c << 12) + (rh << 6) + rw] * wo_[c * 9 + i * 3 + j];
      }
    }
  out[idx] = acc;
}

extern "C" void kernel_launch(void* const* d_in, const int* in_sizes, int n_in,
                              void* d_out, int out_size, void* d_ws, size_t ws_size,
                              hipStream_t stream) {
  const float* in   = (const float*)d_in[0];
  const float* w    = (const float*)d_in[1];
  const float* bias = (const float*)d_in[2];
  const int*   selh = (const int*)d_in[3];
  const int*   selw = (const int*)d_in[4];
  float* out = (float*)d_out;

  if (ws_size >= (size_t)WPRE_BYTES) {
    unsigned short* wpre = (unsigned short*)d_ws;
    wprep<<<dim3(1152), dim3(256), 0, stream>>>(w, wpre);
    sconv_mfma<<<dim3(256), dim3(512), 0, stream>>>(in, wpre, bias, selh, selw, out);
  } else {
    sconv_naive<<<dim3(32768), dim3(256), 0, stream>>>(in, w, bias, selh, selw, out);
  }
}

// Round 2
// 52.215 us; speedup vs baseline: 2.2546x; 2.2546x over previous
//
#include <hip/hip_runtime.h>
#include <hip/hip_bf16.h>

// SConv2dAvg: stride-2 conv with per-output-pixel stochastic tap selection.
// B=32 C=128 H=W=64, O=256 kh=kw=3, oh=ow=32, PAD=1, STRIDE=2.
//
// 3-kernel plan:
//  1) wprep:     weight fp32 [O][C][3][3] -> bf16 wpre[18][256][64], K ordered
//                k = tap*128 + c, LDS XOR swizzle pre-baked per o.
//  2) transform: input fp32 NCHW -> bf16 channels-last HALO-PADDED
//                tp[b][66][66][128] (zero border -> no bounds checks).
//  3) sconv_mfma2: implicit GEMM 128o x 128pix tiles, K-step 64,
//                all staging via global_load_lds (A-gather source is per-lane).

typedef short bf16x8 __attribute__((ext_vector_type(8)));
typedef float f32x4  __attribute__((ext_vector_type(4)));

#define KSTEPS 18
#define WPRE_BYTES (KSTEPS * 256 * 64 * 2)          // 589824
#define TRANS_BYTES (32 * 66 * 66 * 128 * 2)        // 35684352
#define TOTAL_WS (WPRE_BYTES + TRANS_BYTES)

// round-to-nearest-even fp32 -> bf16
__device__ __forceinline__ unsigned short f2bf(float x) {
  unsigned u = __float_as_uint(x);
  return (unsigned short)((u + 0x7fffu + ((u >> 16) & 1u)) >> 16);
}
__device__ __forceinline__ unsigned pk2(float a, float b) {
  unsigned ua = __float_as_uint(a), ub = __float_as_uint(b);
  return ((ua + 0x7fffu + ((ua >> 16) & 1u)) >> 16) |
         ((ub + 0x7fffu + ((ub >> 16) & 1u)) & 0xffff0000u);
}
__device__ __forceinline__ bf16x8 ld_frag(const uint4* a) {
  union { uint4 u; bf16x8 s; } cv; cv.u = *a; return cv.s;
}
__device__ __forceinline__ void async16(const void* g, void* l) {
  __builtin_amdgcn_global_load_lds(
      (__attribute__((address_space(1))) void*)(void*)g,
      (__attribute__((address_space(3))) void*)l, 16, 0, 0);
}

// -------- pre-pass 1: weight -> bf16 wpre[18][256][64], swizzle baked -------
__global__ __launch_bounds__(256) void wprep(const float* __restrict__ w,
                                             unsigned short* __restrict__ wpre) {
  int idx = (blockIdx.x << 8) + threadIdx.x;
  if (idx >= KSTEPS * 16384) return;
  int k_in = idx & 63;
  int o    = (idx >> 6) & 255;
  int kk   = idx >> 14;
  int kg   = (kk << 6) + (k_in ^ ((o & 7) << 3));
  int tap  = kg >> 7;
  int c    = kg & 127;
  int di   = (tap >= 6) ? 2 : ((tap >= 3) ? 1 : 0);
  int dj   = tap - di * 3;
  wpre[idx] = f2bf(w[(o * 128 + c) * 9 + di * 3 + dj]);
}

// -------- pre-pass 2: NCHW fp32 -> padded NHWC bf16 tp[32][66][66][128] -----
// grid (66, 32): one (h'-row, b) per block. LDS transpose [c][w] pad 65.
__global__ __launch_bounds__(256) void transform(const float* __restrict__ in,
                                                 unsigned short* __restrict__ tp) {
  __shared__ float lds[128 * 65];
  const int hp  = blockIdx.x;   // 0..65 padded row
  const int b   = blockIdx.y;
  const int tid = threadIdx.x;
  uint4* rowp = (uint4*)(tp + (size_t)(b * 66 + hp) * 66 * 128);
  uint4 z; z.x = z.y = z.z = z.w = 0u;
  if (hp == 0 || hp == 65) {                 // zero border rows
    for (int s = tid; s < 1056; s += 256) rowp[s] = z;
    return;
  }
  const int h = hp - 1;
  const float* src = in + ((size_t)b << 19) + (h << 6);
  const int w = tid & 63, c0 = tid >> 6;
#pragma unroll
  for (int pass = 0; pass < 32; ++pass) {
    int c = (pass << 2) + c0;
    lds[c * 65 + w] = src[((size_t)c << 12) + w];  // coalesced 256B rows
  }
  __syncthreads();
  for (int s = tid; s < 1056; s += 256) {
    if (s < 16 || s >= 1040) { rowp[s] = z; continue; }   // zero border cols
    int idx = s - 16;
    int wq = idx >> 4, c8 = idx & 15;
    const float* lp = lds + (c8 << 3) * 65 + wq;
    uint4 d;
    d.x = pk2(lp[0],   lp[65]);
    d.y = pk2(lp[130], lp[195]);
    d.z = pk2(lp[260], lp[325]);
    d.w = pk2(lp[390], lp[455]);
    rowp[s] = d;                                           // coalesced 16B
  }
}

// ----------------------------- main kernel ---------------------------------
// grid 512 = b(32) x y-group(8, 4 rows) x o-half(2). 512 threads / 8 waves.
// Tile 128 o x 128 pix, K-step 64. LDS: A 16KB + B 16KB + bias. 2 blocks/CU.
__global__ __launch_bounds__(512, 4) void sconv_mfma2(
    const unsigned short* __restrict__ tp,   // [32][66][66][128] bf16 padded
    const unsigned short* __restrict__ wpre, // [18][256][64] bf16 pre-swizzled
    const float* __restrict__ bias,
    const int* __restrict__ selh,            // [32][32]
    const int* __restrict__ selw,            // [32][32]
    float* __restrict__ out)                 // [32][256][32][32]
{
  __shared__ uint4 Alds[128 * 8];   // patches [pix][8 slots], swizzled
  __shared__ uint4 Blds[128 * 8];   // weights [o_local][8 slots], swizzle baked
  __shared__ float bias_s[128];

  const int tid   = threadIdx.x;
  const int blk   = blockIdx.x;
  const int b     = blk >> 4;
  const int y0    = ((blk >> 1) & 7) << 2;
  const int ohalf = blk & 1;

  if (tid < 128) bias_s[tid] = bias[(ohalf << 7) + tid];

  // ---- gather role: thread feeds A-slots {tid, tid+512} = pixels {p0,p0+64}
  const int p0 = tid >> 3;          // 0..63
  const int sl = tid & 7;
  int addr0, addr1;                 // padded-pixel index at tap (0,0)
  {
    const int py0 = y0 + (p0 >> 5);
    const int px  = p0 & 31;
    const int sh0 = selh[(py0 << 5) | px], sw0 = selw[(py0 << 5) | px];
    const int py1 = py0 + 2;
    const int sh1 = selh[(py1 << 5) | px], sw1 = selw[(py1 << 5) | px];
    addr0 = (b * 66 + 2 * py0 + sh0) * 66 + 2 * px + sw0;
    addr1 = (b * 66 + 2 * py1 + sh1) * 66 + 2 * px + sw1;
  }
  const int n0 = sl ^ (p0 & 7);     // source chunk (XOR swizzle on source)
  const char* tbase = (const char*)tp;

  // ---- MFMA role
  const int wv = tid >> 6, ln = tid & 63;
  const int wo = wv & 1;            // 2 o-waves x 64 o
  const int wp = wv >> 1;           // 4 p-waves x 32 pix
  const int lo = ln & 15, hi = ln >> 4;

  // B staging: linear; swizzle pre-baked in wpre
  const char* wsrc = (const char*)wpre + (ohalf << 14) + (tid << 4);

  f32x4 acc[4][2] = {};             // [o-frag][pix-frag]

  for (int kk = 0; kk < KSTEPS; ++kk) {
    const int tap = kk >> 1;
    const int di  = (tap >= 6) ? 2 : ((tap >= 3) ? 1 : 0);
    const int dj  = tap - 3 * di;
    const int toff = ((di * 66 + dj) << 8) + ((kk & 1) << 7) + (n0 << 4);

    // A gather: 2 x global_load_lds, per-lane source, 128B/pixel contiguous
    async16(tbase + ((size_t)addr0 << 8) + toff, Alds + (wv << 6));
    async16(tbase + ((size_t)addr1 << 8) + toff, Alds + (wv << 6) + 512);
    // B stage: 2 x global_load_lds, linear 16KB
    async16(wsrc + (kk << 15),        Blds + (wv << 6));
    async16(wsrc + (kk << 15) + 8192, Blds + (wv << 6) + 512);

    __syncthreads();   // drains vmcnt + lgkm for all waves

    bf16x8 FW[4][2], FP[2][2];
#pragma unroll
    for (int f = 0; f < 4; ++f) {
      const int orow = (wo << 6) + (f << 4) + lo;
#pragma unroll
      for (int ks = 0; ks < 2; ++ks)
        FW[f][ks] = ld_frag(Blds + (orow << 3) + (((ks << 2) | hi) ^ (orow & 7)));
    }
#pragma unroll
    for (int f = 0; f < 2; ++f) {
      const int prow = (wp << 5) + (f << 4) + lo;
#pragma unroll
      for (int ks = 0; ks < 2; ++ks)
        FP[f][ks] = ld_frag(Alds + (prow << 3) + (((ks << 2) | hi) ^ (prow & 7)));
    }
#pragma unroll
    for (int fo = 0; fo < 4; ++fo)
#pragma unroll
      for (int fp = 0; fp < 2; ++fp)
#pragma unroll
        for (int ks = 0; ks < 2; ++ks)
          acc[fo][fp] = __builtin_amdgcn_mfma_f32_16x16x32_bf16(
              FW[fo][ks], FP[fp][ks], acc[fo][fp], 0, 0, 0);

    __syncthreads();
  }

  // ---- epilogue: D row = o (hi*4+j), col = pix (lo); +bias; coalesced f32
  float* ob = out + ((size_t)b << 18) + ((size_t)ohalf << 17) + (y0 << 5);
#pragma unroll
  for (int fo = 0; fo < 4; ++fo) {
    const int obase = (wo << 6) + (fo << 4) + (hi << 2);
#pragma unroll
    for (int fp = 0; fp < 2; ++fp) {
      const int pix = (wp << 5) + (fp << 4) + lo;
#pragma unroll
      for (int j = 0; j < 4; ++j) {
        const int o = obase + j;
        ob[((size_t)o << 10) + pix] = acc[fo][fp][j] + bias_s[o];
      }
    }
  }
}

// ------------- mid-tier fallback: round-1 kernel (fp32 gather) -------------
__global__ __launch_bounds__(512, 2) void sconv_mfma(
    const float* __restrict__ in, const unsigned short* __restrict__ wpre,
    const float* __restrict__ bias, const int* __restrict__ selh,
    const int* __restrict__ selw, float* __restrict__ out) {
  __shared__ uint4 Alds[128 * 8];
  __shared__ uint4 Blds[256 * 8];
  __shared__ float bias_s[256];
  const int tid = threadIdx.x;
  const int blk = blockIdx.x;
  const int b   = blk >> 3;
  const int y0  = (blk & 7) << 2;
  if (tid < 256) bias_s[tid] = bias[tid];
  const int p    = tid & 127;
  const int csub = tid >> 7;
  const int py   = y0 + (p >> 5);
  const int px   = p & 31;
  const int rh0  = 2 * py + selh[(py << 5) | px] - 1;
  const int rw0  = 2 * px + selw[(py << 5) | px] - 1;
  const float* inb = in + ((size_t)b << 19);
  const int wv = tid >> 6, ln = tid & 63;
  const int wo = wv & 3, wp = wv >> 2;
  const int lo = ln & 15, hi = ln >> 4;
  f32x4 acc[4][4] = {};
  for (int kk = 0; kk < KSTEPS; ++kk) {
    const int tap = kk >> 1;
    const int di  = (tap >= 6) ? 2 : ((tap >= 3) ? 1 : 0);
    const int dj  = tap - di * 3;
    const int rh  = rh0 + di;
    const int rw  = rw0 + dj;
    const bool ok = (rh >= 0) & (rh < 64) & (rw >= 0) & (rw < 64);
    {
      const char* gbase = (const char*)wpre + ((size_t)kk << 15);
#pragma unroll
      for (int r = 0; r < 4; ++r) {
        int chunk = (wv << 2) + r;
        async16(gbase + (chunk << 10) + (ln << 4), Blds + (chunk << 6));
      }
    }
    {
      const float* src = inb + ((size_t)(((kk & 1) << 6) + (csub << 4)) << 12)
                             + (rh << 6) + rw;
      float v[16];
#pragma unroll
      for (int cc = 0; cc < 16; ++cc)
        v[cc] = ok ? src[(size_t)cc << 12] : 0.f;
#pragma unroll
      for (int z = 0; z < 2; ++z) {
        uint4 d;
        d.x = pk2(v[z * 8 + 0], v[z * 8 + 1]);
        d.y = pk2(v[z * 8 + 2], v[z * 8 + 3]);
        d.z = pk2(v[z * 8 + 4], v[z * 8 + 5]);
        d.w = pk2(v[z * 8 + 6], v[z * 8 + 7]);
        int slot = ((csub << 1) | z) ^ (p & 7);
        Alds[(p << 3) + slot] = d;
      }
    }
    __syncthreads();
    bf16x8 FW[4][2], FP[4][2];
#pragma unroll
    for (int f = 0; f < 4; ++f) {
      const int orow = (wo << 6) + (f << 4) + lo;
      const int prow = (wp << 6) + (f << 4) + lo;
#pragma unroll
      for (int ks = 0; ks < 2; ++ks) {
        FW[f][ks] = ld_frag(Blds + (orow << 3) + (((ks << 2) | hi) ^ (orow & 7)));
        FP[f][ks] = ld_frag(Alds + (prow << 3) + (((ks << 2) | hi) ^ (prow & 7)));
      }
    }
#pragma unroll
    for (int fo = 0; fo < 4; ++fo)
#pragma unroll
      for (int fp = 0; fp < 4; ++fp)
#pragma unroll
        for (int ks = 0; ks < 2; ++ks)
          acc[fo][fp] = __builtin_amdgcn_mfma_f32_16x16x32_bf16(
              FW[fo][ks], FP[fp][ks], acc[fo][fp], 0, 0, 0);
    __syncthreads();
  }
  float* ob = out + ((size_t)b << 18) + (y0 << 5);
#pragma unroll
  for (int fo = 0; fo < 4; ++fo) {
    const int obase = (wo << 6) + (fo << 4) + (hi << 2);
#pragma unroll
    for (int fp = 0; fp < 4; ++fp) {
      const int pix = (wp << 6) + (fp << 4) + lo;
#pragma unroll
      for (int j = 0; j < 4; ++j) {
        const int o = obase + j;
        ob[((size_t)o << 10) + pix] = acc[fo][fp][j] + bias_s[o];
      }
    }
  }
}

// ------------------- exact fp32 fallback (ws too small) --------------------
__global__ __launch_bounds__(256) void sconv_naive(
    const float* __restrict__ in, const float* __restrict__ w,
    const float* __restrict__ bias, const int* __restrict__ selh,
    const int* __restrict__ selw, float* __restrict__ out) {
  int idx = (blockIdx.x << 8) + threadIdx.x;
  if (idx >= 32 * 256 * 32 * 32) return;
  int x = idx & 31, y = (idx >> 5) & 31, o = (idx >> 10) & 255, b = idx >> 18;
  int rh0 = 2 * y + selh[(y << 5) | x] - 1;
  int rw0 = 2 * x + selw[(y << 5) | x] - 1;
  const float* inb = in + ((size_t)b << 19);
  const float* wo_ = w + o * 1152;
  float acc = bias[o];
  for (int c = 0; c < 128; ++c)
    for (int i = 0; i < 3; ++i) {
      int rh = rh0 + i;
      if (rh < 0 || rh >= 64) continue;
      for (int j = 0; j < 3; ++j) {
        int rw = rw0 + j;
        if (rw < 0 || rw >= 64) continue;
        acc += inb[(c << 12) + (rh << 6) + rw] * wo_[c * 9 + i * 3 + j];
      }
    }
  out[idx] = acc;
}

extern "C" void kernel_launch(void* const* d_in, const int* in_sizes, int n_in,
                              void* d_out, int out_size, void* d_ws, size_t ws_size,
                              hipStream_t stream) {
  const float* in   = (const float*)d_in[0];
  const float* w    = (const float*)d_in[1];
  const float* bias = (const float*)d_in[2];
  const int*   selh = (const int*)d_in[3];
  const int*   selw = (const int*)d_in[4];
  float* out = (float*)d_out;

  if (ws_size >= (size_t)TOTAL_WS) {
    unsigned short* wpre = (unsigned short*)d_ws;
    unsigned short* tp   = (unsigned short*)((char*)d_ws + WPRE_BYTES);
    wprep<<<dim3(1152), dim3(256), 0, stream>>>(w, wpre);
    transform<<<dim3(66, 32), dim3(256), 0, stream>>>(in, tp);
    sconv_mfma2<<<dim3(512), dim3(512), 0, stream>>>(tp, wpre, bias, selh, selw, out);
  } else if (ws_size >= (size_t)WPRE_BYTES) {
    unsigned short* wpre = (unsigned short*)d_ws;
    wprep<<<dim3(1152), dim3(256), 0, stream>>>(w, wpre);
    sconv_mfma<<<dim3(256), dim3(512), 0, stream>>>(in, wpre, bias, selh, selw, out);
  } else {
    sconv_naive<<<dim3(32768), dim3(256), 0, stream>>>(in, w, bias, selh, selw, out);
  }
}

// Round 3
// 47.738 us; speedup vs baseline: 2.4660x; 1.0938x over previous
//
#include <hip/hip_runtime.h>
#include <hip/hip_bf16.h>

// SConv2dAvg: stride-2 conv with per-output-pixel stochastic tap selection.
// B=32 C=128 H=W=64, O=256 kh=kw=3, oh=ow=32, PAD=1, STRIDE=2.
//
// Plan:
//  1) prep (fused): weight fp32 -> bf16 wpre[18][256][64] (K = tap*128+c,
//     XOR swizzle baked), and input NCHW fp32 -> bf16 padded NHWC
//     tp[32][66][66][128] (zero halo -> no bounds checks in main loop).
//  2) sconv_mfma3: implicit GEMM 128o x 128pix tiles, K-step 64,
//     double-buffered LDS with counted vmcnt (T3/T4), XCD-chunked swizzle.

typedef short bf16x8 __attribute__((ext_vector_type(8)));
typedef float f32x4  __attribute__((ext_vector_type(4)));

#define KSTEPS 18
#define WPRE_BYTES (KSTEPS * 256 * 64 * 2)          // 589824
#define TRANS_BYTES (32 * 66 * 66 * 128 * 2)        // 35684352
#define TOTAL_WS (WPRE_BYTES + TRANS_BYTES)

__device__ __forceinline__ unsigned short f2bf(float x) {
  unsigned u = __float_as_uint(x);
  return (unsigned short)((u + 0x7fffu + ((u >> 16) & 1u)) >> 16);
}
__device__ __forceinline__ unsigned pk2(float a, float b) {
  unsigned ua = __float_as_uint(a), ub = __float_as_uint(b);
  return ((ua + 0x7fffu + ((ua >> 16) & 1u)) >> 16) |
         ((ub + 0x7fffu + ((ub >> 16) & 1u)) & 0xffff0000u);
}
__device__ __forceinline__ bf16x8 ld_frag(const uint4* a) {
  union { uint4 u; bf16x8 s; } cv; cv.u = *a; return cv.s;
}
__device__ __forceinline__ void async16(const void* g, void* l) {
  __builtin_amdgcn_global_load_lds(
      (__attribute__((address_space(1))) void*)(void*)g,
      (__attribute__((address_space(3))) void*)l, 16, 0, 0);
}

// ---------------- fused pre-pass: transform + wprep ------------------------
// grid (84, 32): blockIdx.x < 66 -> padded-NHWC transform of one (row, b);
//                blockIdx.x >= 66 -> wprep slice kk = x-66, o-block = y.
__global__ __launch_bounds__(256) void prep(const float* __restrict__ in,
                                            const float* __restrict__ w,
                                            unsigned short* __restrict__ tp,
                                            unsigned short* __restrict__ wpre) {
  const int tid = threadIdx.x;
  if (blockIdx.x >= 66) {   // ---- weight prep: 8 o-rows x 64 k per block ----
    const int kk = blockIdx.x - 66;
    const int ob = blockIdx.y;            // o in [ob*8, ob*8+8)
#pragma unroll
    for (int e = 0; e < 2; ++e) {
      int t2   = (tid << 1) + e;          // 0..511
      int o    = (ob << 3) + (t2 >> 6);
      int k_in = t2 & 63;
      int kg   = (kk << 6) + (k_in ^ ((o & 7) << 3));
      int tap  = kg >> 7;
      int c    = kg & 127;
      int di   = (tap >= 6) ? 2 : ((tap >= 3) ? 1 : 0);
      int dj   = tap - di * 3;
      wpre[(kk << 14) + (o << 6) + k_in] = f2bf(w[(o * 128 + c) * 9 + di * 3 + dj]);
    }
    return;
  }
  // ---- input transform ----
  __shared__ float lds[128 * 65];
  const int hp = blockIdx.x;   // 0..65 padded row
  const int b  = blockIdx.y;
  uint4* rowp = (uint4*)(tp + (size_t)(b * 66 + hp) * 66 * 128);
  uint4 z; z.x = z.y = z.z = z.w = 0u;
  if (hp == 0 || hp == 65) {                 // zero border rows
    for (int s = tid; s < 1056; s += 256) rowp[s] = z;
    return;
  }
  const int h = hp - 1;
  const float* src = in + ((size_t)b << 19) + (h << 6);
  const int ww = tid & 63, c0 = tid >> 6;
#pragma unroll
  for (int pass = 0; pass < 32; ++pass) {
    int c = (pass << 2) + c0;
    lds[c * 65 + ww] = src[((size_t)c << 12) + ww];  // coalesced
  }
  __syncthreads();
  for (int s = tid; s < 1056; s += 256) {
    if (s < 16 || s >= 1040) { rowp[s] = z; continue; }   // zero border cols
    int idx = s - 16;
    int wq = idx >> 4, c8 = idx & 15;
    const float* lp = lds + (c8 << 3) * 65 + wq;
    uint4 d;
    d.x = pk2(lp[0],   lp[65]);
    d.y = pk2(lp[130], lp[195]);
    d.z = pk2(lp[260], lp[325]);
    d.w = pk2(lp[390], lp[455]);
    rowp[s] = d;
  }
}

// ----------------------------- main kernel ---------------------------------
// grid 512 (XCD-chunked swizzle), 512 threads / 8 waves.
// Tile 128 o x 128 pix, K-step 64, double-buffered LDS (A 2x16KB, B 2x16KB).
__global__ __launch_bounds__(512, 4) void sconv_mfma3(
    const unsigned short* __restrict__ tp,   // [32][66][66][128] bf16 padded
    const unsigned short* __restrict__ wpre, // [18][256][64] bf16 pre-swizzled
    const float* __restrict__ bias,
    const int* __restrict__ selh,            // [32][32]
    const int* __restrict__ selw,            // [32][32]
    float* __restrict__ out)                 // [32][256][32][32]
{
  __shared__ uint4 Alds[2][1024];   // patches [pix][8 slots], swizzled
  __shared__ uint4 Blds[2][1024];   // weights [o_local][8 slots], swz baked
  __shared__ float bias_s[128];

  const int tid = threadIdx.x;
  // XCD-chunked swizzle: consecutive logical tiles on one XCD (T1)
  const int d    = blockIdx.x;
  const int blk  = ((d & 7) << 6) + (d >> 3);   // 512 = 8 * 64, bijective
  const int b     = blk >> 4;
  const int y0    = ((blk >> 1) & 7) << 2;
  const int ohalf = blk & 1;

  if (tid < 128) bias_s[tid] = bias[(ohalf << 7) + tid];

  // ---- gather role: thread feeds A-slots {tid, tid+512} = pixels {p0,p0+64}
  const int p0 = tid >> 3;          // 0..63
  const int sl = tid & 7;
  int addr0, addr1;                 // padded-pixel index at tap (0,0)
  {
    const int py0 = y0 + (p0 >> 5);
    const int px  = p0 & 31;
    const int sh0 = selh[(py0 << 5) | px], sw0 = selw[(py0 << 5) | px];
    const int py1 = py0 + 2;
    const int sh1 = selh[(py1 << 5) | px], sw1 = selw[(py1 << 5) | px];
    addr0 = (b * 66 + 2 * py0 + sh0) * 66 + 2 * px + sw0;
    addr1 = (b * 66 + 2 * py1 + sh1) * 66 + 2 * px + sw1;
  }
  const int n0 = sl ^ (p0 & 7);     // XOR swizzle folded into source chunk
  const char* tbase = (const char*)tp;

  // ---- MFMA role
  const int wv = tid >> 6, ln = tid & 63;
  const int wo = wv & 1;            // 2 o-waves x 64 o
  const int wp = wv >> 1;           // 4 p-waves x 32 pix
  const int lo = ln & 15, hi = ln >> 4;

  const char* wsrc = (const char*)wpre + (ohalf << 14) + (tid << 4);

  f32x4 acc[4][2] = {};             // [o-frag][pix-frag]

#define STAGE(BUF, KK)                                                        \
  do {                                                                        \
    const int tap_ = (KK) >> 1;                                               \
    const int di_  = (tap_ >= 6) ? 2 : ((tap_ >= 3) ? 1 : 0);                 \
    const int dj_  = tap_ - 3 * di_;                                          \
    const int toff_ = ((di_ * 66 + dj_) << 8) + (((KK) & 1) << 7) + (n0 << 4);\
    uint4* A_ = &Alds[BUF][0];                                                \
    uint4* B_ = &Blds[BUF][0];                                                \
    async16(tbase + ((size_t)addr0 << 8) + toff_, A_ + (wv << 6));            \
    async16(tbase + ((size_t)addr1 << 8) + toff_, A_ + (wv << 6) + 512);      \
    async16(wsrc + ((KK) << 15),        B_ + (wv << 6));                      \
    async16(wsrc + ((KK) << 15) + 8192, B_ + (wv << 6) + 512);                \
  } while (0)

  STAGE(0, 0);                       // prologue: 4 loads in flight
  int cur = 0;

  for (int kk = 0; kk < KSTEPS; ++kk) {
    if (kk < KSTEPS - 1) {
      STAGE(cur ^ 1, kk + 1);                              // 4 newest in flight
      asm volatile("s_waitcnt vmcnt(4)" ::: "memory");     // cur's loads landed
    } else {
      asm volatile("s_waitcnt vmcnt(0)" ::: "memory");
    }
    __builtin_amdgcn_s_barrier();          // all waves' cur-loads in LDS
    asm volatile("" ::: "memory");         // pin ds_reads below the barrier

    const uint4* A = &Alds[cur][0];
    const uint4* B = &Blds[cur][0];
    bf16x8 FW[4][2], FP[2][2];
#pragma unroll
    for (int f = 0; f < 4; ++f) {
      const int orow = (wo << 6) + (f << 4) + lo;
#pragma unroll
      for (int ks = 0; ks < 2; ++ks)
        FW[f][ks] = ld_frag(B + (orow << 3) + (((ks << 2) | hi) ^ (orow & 7)));
    }
#pragma unroll
    for (int f = 0; f < 2; ++f) {
      const int prow = (wp << 5) + (f << 4) + lo;
#pragma unroll
      for (int ks = 0; ks < 2; ++ks)
        FP[f][ks] = ld_frag(A + (prow << 3) + (((ks << 2) | hi) ^ (prow & 7)));
    }
#pragma unroll
    for (int fo = 0; fo < 4; ++fo)
#pragma unroll
      for (int fp = 0; fp < 2; ++fp)
#pragma unroll
        for (int ks = 0; ks < 2; ++ks)
          acc[fo][fp] = __builtin_amdgcn_mfma_f32_16x16x32_bf16(
              FW[fo][ks], FP[fp][ks], acc[fo][fp], 0, 0, 0);

    asm volatile("s_waitcnt lgkmcnt(0)" ::: "memory");  // reads complete
    __builtin_amdgcn_s_barrier();          // before next STAGE overwrites cur
    asm volatile("" ::: "memory");
    cur ^= 1;
  }
#undef STAGE

  // ---- epilogue: D row = o (hi*4+j), col = pix (lo); +bias
  float* ob = out + ((size_t)b << 18) + ((size_t)ohalf << 17) + (y0 << 5);
#pragma unroll
  for (int fo = 0; fo < 4; ++fo) {
    const int obase = (wo << 6) + (fo << 4) + (hi << 2);
#pragma unroll
    for (int fp = 0; fp < 2; ++fp) {
      const int pix = (wp << 5) + (fp << 4) + lo;
#pragma unroll
      for (int j = 0; j < 4; ++j) {
        const int o = obase + j;
        ob[((size_t)o << 10) + pix] = acc[fo][fp][j] + bias_s[o];
      }
    }
  }
}

// ------------------- exact fp32 fallback (ws too small) --------------------
__global__ __launch_bounds__(256) void sconv_naive(
    const float* __restrict__ in, const float* __restrict__ w,
    const float* __restrict__ bias, const int* __restrict__ selh,
    const int* __restrict__ selw, float* __restrict__ out) {
  int idx = (blockIdx.x << 8) + threadIdx.x;
  if (idx >= 32 * 256 * 32 * 32) return;
  int x = idx & 31, y = (idx >> 5) & 31, o = (idx >> 10) & 255, b = idx >> 18;
  int rh0 = 2 * y + selh[(y << 5) | x] - 1;
  int rw0 = 2 * x + selw[(y << 5) | x] - 1;
  const float* inb = in + ((size_t)b << 19);
  const float* wo_ = w + o * 1152;
  float acc = bias[o];
  for (int c = 0; c < 128; ++c)
    for (int i = 0; i < 3; ++i) {
      int rh = rh0 + i;
      if (rh < 0 || rh >= 64) continue;
      for (int j = 0; j < 3; ++j) {
        int rw = rw0 + j;
        if (rw < 0 || rw >= 64) continue;
        acc += inb[(c << 12) + (rh << 6) + rw] * wo_[c * 9 + i * 3 + j];
      }
    }
  out[idx] = acc;
}

extern "C" void kernel_launch(void* const* d_in, const int* in_sizes, int n_in,
                              void* d_out, int out_size, void* d_ws, size_t ws_size,
                              hipStream_t stream) {
  const float* in   = (const float*)d_in[0];
  const float* w    = (const float*)d_in[1];
  const float* bias = (const float*)d_in[2];
  const int*   selh = (const int*)d_in[3];
  const int*   selw = (const int*)d_in[4];
  float* out = (float*)d_out;

  if (ws_size >= (size_t)TOTAL_WS) {
    unsigned short* wpre = (unsigned short*)d_ws;
    unsigned short* tp   = (unsigned short*)((char*)d_ws + WPRE_BYTES);
    prep<<<dim3(84, 32), dim3(256), 0, stream>>>(in, w, tp, wpre);
    sconv_mfma3<<<dim3(512), dim3(512), 0, stream>>>(tp, wpre, bias, selh, selw, out);
  } else {
    sconv_naive<<<dim3(32768), dim3(256), 0, stream>>>(in, w, bias, selh, selw, out);
  }
}

// Round 4
// 45.307 us; speedup vs baseline: 2.5984x; 1.0537x over previous
//
#include <hip/hip_runtime.h>
#include <hip/hip_bf16.h>

// SConv2dAvg: stride-2 conv with per-output-pixel stochastic tap selection.
// B=32 C=128 H=W=64, O=256 kh=kw=3, oh=ow=32, PAD=1, STRIDE=2.
//
// Plan:
//  1) prep (fused): weight fp32 -> bf16 wpre[36][256][32] (K = tap*128+c,
//     K-step 32, 2-bit XOR swizzle baked), and input NCHW fp32 -> bf16 padded
//     NHWC tp[32][66][66][128] (zero halo -> no bounds checks in main loop).
//  2) sconv_mfma4: implicit GEMM 128o x 128pix tiles, K-step 32,
//     4 LDS buffers, 2-deep prefetch, 1 barrier/step, counted vmcnt (T3/T4),
//     XCD-chunked block swizzle (T1).

typedef short bf16x8 __attribute__((ext_vector_type(8)));
typedef float f32x4  __attribute__((ext_vector_type(4)));

#define NSTEP 36
#define WPRE_BYTES (NSTEP * 256 * 32 * 2)           // 589824
#define TRANS_BYTES (32 * 66 * 66 * 128 * 2)        // 35684352
#define TOTAL_WS (WPRE_BYTES + TRANS_BYTES)

__device__ __forceinline__ unsigned short f2bf(float x) {
  unsigned u = __float_as_uint(x);
  return (unsigned short)((u + 0x7fffu + ((u >> 16) & 1u)) >> 16);
}
__device__ __forceinline__ unsigned pk2(float a, float b) {
  unsigned ua = __float_as_uint(a), ub = __float_as_uint(b);
  return ((ua + 0x7fffu + ((ua >> 16) & 1u)) >> 16) |
         ((ub + 0x7fffu + ((ub >> 16) & 1u)) & 0xffff0000u);
}
__device__ __forceinline__ bf16x8 ld_frag(const uint4* a) {
  union { uint4 u; bf16x8 s; } cv; cv.u = *a; return cv.s;
}
__device__ __forceinline__ void async16(const void* g, void* l) {
  __builtin_amdgcn_global_load_lds(
      (__attribute__((address_space(1))) void*)(void*)g,
      (__attribute__((address_space(3))) void*)l, 16, 0, 0);
}

// ---------------- fused pre-pass: transform + wprep ------------------------
// grid (102, 32): x < 66 -> padded-NHWC transform of (row hp=x, batch y);
//                 x >= 66 -> wprep K-slice s = x-66, o-block = y (8 o's).
__global__ __launch_bounds__(256) void prep(const float* __restrict__ in,
                                            const float* __restrict__ w,
                                            unsigned short* __restrict__ tp,
                                            unsigned short* __restrict__ wpre) {
  const int tid = threadIdx.x;
  if (blockIdx.x >= 66) {   // ---- weight prep: wpre[s][o][32], swizzle baked
    const int s    = blockIdx.x - 66;       // 0..35
    const int o    = (blockIdx.y << 3) + (tid >> 5);
    const int k_in = tid & 31;
    const int kg   = (s << 5) + (((k_in >> 3) ^ ((o >> 1) & 3)) << 3) + (k_in & 7);
    const int tap  = kg >> 7;
    const int c    = kg & 127;
    const int di   = (tap >= 6) ? 2 : ((tap >= 3) ? 1 : 0);
    const int dj   = tap - di * 3;
    wpre[(s << 13) + (o << 5) + k_in] = f2bf(w[(o * 128 + c) * 9 + di * 3 + dj]);
    return;
  }
  // ---- input transform ----
  __shared__ float lds[128 * 65];
  const int hp = blockIdx.x;   // 0..65 padded row
  const int b  = blockIdx.y;
  uint4* rowp = (uint4*)(tp + (size_t)(b * 66 + hp) * 66 * 128);
  uint4 z; z.x = z.y = z.z = z.w = 0u;
  if (hp == 0 || hp == 65) {                 // zero border rows
    for (int s = tid; s < 1056; s += 256) rowp[s] = z;
    return;
  }
  const int h = hp - 1;
  const float* src = in + ((size_t)b << 19) + (h << 6);
  const int ww4 = (tid & 15) << 2;
  const int c0  = tid >> 4;
#pragma unroll
  for (int pass = 0; pass < 8; ++pass) {
    int c = (pass << 4) + c0;
    float4 v = *(const float4*)(src + ((size_t)c << 12) + ww4);  // coalesced
    float* lp = lds + c * 65 + ww4;
    lp[0] = v.x; lp[1] = v.y; lp[2] = v.z; lp[3] = v.w;
  }
  __syncthreads();
  for (int s = tid; s < 1056; s += 256) {
    if (s < 16 || s >= 1040) { rowp[s] = z; continue; }   // zero border cols
    int idx = s - 16;
    int wq = idx >> 4, c8 = idx & 15;
    const float* lp = lds + (c8 << 3) * 65 + wq;
    uint4 d;
    d.x = pk2(lp[0],   lp[65]);
    d.y = pk2(lp[130], lp[195]);
    d.z = pk2(lp[260], lp[325]);
    d.w = pk2(lp[390], lp[455]);
    rowp[s] = d;
  }
}

// ----------------------------- main kernel ---------------------------------
// grid 512 (XCD-chunked), 512 threads / 8 waves. Tile 128o x 128pix,
// K-step 32, 4 LDS buffers (A 8KB + B 8KB each), 2-deep prefetch,
// one barrier per step, counted vmcnt (never 0 in steady loop).
__global__ __launch_bounds__(512, 4) void sconv_mfma4(
    const unsigned short* __restrict__ tp,   // [32][66][66][128] bf16 padded
    const unsigned short* __restrict__ wpre, // [36][256][32] bf16 pre-swizzled
    const float* __restrict__ bias,
    const int* __restrict__ selh,            // [32][32]
    const int* __restrict__ selw,            // [32][32]
    float* __restrict__ out)                 // [32][256][32][32]
{
  __shared__ uint4 Alds[4][512];   // patches [pix(128)][4 slots], 8KB/buf
  __shared__ uint4 Blds[4][512];   // weights [o_local(128)][4 slots], swz baked
  __shared__ float bias_s[128];

  const int tid = threadIdx.x;
  // XCD-chunked swizzle (T1): 512 = 8 XCDs x 64 consecutive logical tiles
  const int d0    = blockIdx.x;
  const int blk   = ((d0 & 7) << 6) + (d0 >> 3);
  const int b     = blk >> 4;
  const int y0    = ((blk >> 1) & 7) << 2;
  const int ohalf = blk & 1;

  if (tid < 128) bias_s[tid] = bias[(ohalf << 7) + tid];

  // ---- gather role: thread owns pixel p0, 16B chunk sl of its 64B k-row
  const int p0 = tid >> 2;          // 0..127
  const int sl = tid & 3;
  int addr0;                        // padded-pixel index at tap (0,0)
  {
    const int py = y0 + (p0 >> 5);
    const int px = p0 & 31;
    addr0 = (b * 66 + 2 * py + selh[(py << 5) | px]) * 66
          + 2 * px + selw[(py << 5) | px];
  }
  const int u0 = sl ^ ((p0 >> 1) & 3);   // 2-bit XOR swizzle on source chunk
  const char* tbase = (const char*)tp;

  // ---- MFMA role
  const int wv = tid >> 6, ln = tid & 63;
  const int wo = wv & 1;            // 2 o-waves x 64 o
  const int wp = wv >> 1;           // 4 p-waves x 32 pix
  const int lo = ln & 15, hi = ln >> 4;

  const char* wsrc = (const char*)wpre + (ohalf << 13) + (tid << 4);

  f32x4 acc[4][2] = {};             // [o-frag][pix-frag]

#define STAGE(BUF, KK)                                                        \
  do {                                                                        \
    const int tap_ = (KK) >> 2;                                               \
    const int di_  = (tap_ >= 6) ? 2 : ((tap_ >= 3) ? 1 : 0);                 \
    const int dj_  = tap_ - 3 * di_;                                          \
    const int toff_ = ((di_ * 66 + dj_) << 8) + (((KK) & 3) << 6) + (u0 << 4);\
    async16(tbase + ((size_t)addr0 << 8) + toff_, &Alds[BUF][wv << 6]);       \
    async16(wsrc + ((KK) << 14), &Blds[BUF][wv << 6]);                        \
  } while (0)

#define DO_MMA(BUF)                                                           \
  do {                                                                        \
    const uint4* A_ = &Alds[BUF][0];                                          \
    const uint4* B_ = &Blds[BUF][0];                                          \
    bf16x8 FW[4], FP[2];                                                      \
    _Pragma("unroll")                                                         \
    for (int f = 0; f < 4; ++f) {                                             \
      const int orow = (wo << 6) + (f << 4) + lo;                             \
      FW[f] = ld_frag(B_ + (orow << 2) + (hi ^ ((orow >> 1) & 3)));           \
    }                                                                         \
    _Pragma("unroll")                                                         \
    for (int f = 0; f < 2; ++f) {                                             \
      const int prow = (wp << 5) + (f << 4) + lo;                             \
      FP[f] = ld_frag(A_ + (prow << 2) + (hi ^ ((prow >> 1) & 3)));           \
    }                                                                         \
    _Pragma("unroll")                                                         \
    for (int fo = 0; fo < 4; ++fo)                                            \
      _Pragma("unroll")                                                       \
      for (int fp = 0; fp < 2; ++fp)                                          \
        acc[fo][fp] = __builtin_amdgcn_mfma_f32_16x16x32_bf16(                \
            FW[fo], FP[fp], acc[fo][fp], 0, 0, 0);                            \
  } while (0)

  STAGE(0, 0);                      // prologue: 2 steps in flight
  STAGE(1, 1);

#pragma unroll 4
  for (int kk = 0; kk < NSTEP - 2; ++kk) {
    STAGE((kk + 2) & 3, kk + 2);                         // 2-deep prefetch
    asm volatile("s_waitcnt vmcnt(4)" ::: "memory");     // step-kk loads landed
    __builtin_amdgcn_s_barrier();
    asm volatile("" ::: "memory");
    DO_MMA(kk & 3);
    asm volatile("s_waitcnt lgkmcnt(0)" ::: "memory");   // reads drained before
  }                                                      // next barrier

  asm volatile("s_waitcnt vmcnt(2)" ::: "memory");       // step 34
  __builtin_amdgcn_s_barrier();
  asm volatile("" ::: "memory");
  DO_MMA(2);
  asm volatile("s_waitcnt lgkmcnt(0)" ::: "memory");

  asm volatile("s_waitcnt vmcnt(0)" ::: "memory");       // step 35
  __builtin_amdgcn_s_barrier();
  asm volatile("" ::: "memory");
  DO_MMA(3);
#undef STAGE
#undef DO_MMA

  // ---- epilogue: D row = o (hi*4+j), col = pix (lo); +bias
  float* ob = out + ((size_t)b << 18) + ((size_t)ohalf << 17) + (y0 << 5);
#pragma unroll
  for (int fo = 0; fo < 4; ++fo) {
    const int obase = (wo << 6) + (fo << 4) + (hi << 2);
#pragma unroll
    for (int fp = 0; fp < 2; ++fp) {
      const int pix = (wp << 5) + (fp << 4) + lo;
#pragma unroll
      for (int j = 0; j < 4; ++j) {
        const int o = obase + j;
        ob[((size_t)o << 10) + pix] = acc[fo][fp][j] + bias_s[o];
      }
    }
  }
}

// ------------------- exact fp32 fallback (ws too small) --------------------
__global__ __launch_bounds__(256) void sconv_naive(
    const float* __restrict__ in, const float* __restrict__ w,
    const float* __restrict__ bias, const int* __restrict__ selh,
    const int* __restrict__ selw, float* __restrict__ out) {
  int idx = (blockIdx.x << 8) + threadIdx.x;
  if (idx >= 32 * 256 * 32 * 32) return;
  int x = idx & 31, y = (idx >> 5) & 31, o = (idx >> 10) & 255, b = idx >> 18;
  int rh0 = 2 * y + selh[(y << 5) | x] - 1;
  int rw0 = 2 * x + selw[(y << 5) | x] - 1;
  const float* inb = in + ((size_t)b << 19);
  const float* wo_ = w + o * 1152;
  float acc = bias[o];
  for (int c = 0; c < 128; ++c)
    for (int i = 0; i < 3; ++i) {
      int rh = rh0 + i;
      if (rh < 0 || rh >= 64) continue;
      for (int j = 0; j < 3; ++j) {
        int rw = rw0 + j;
        if (rw < 0 || rw >= 64) continue;
        acc += inb[(c << 12) + (rh << 6) + rw] * wo_[c * 9 + i * 3 + j];
      }
    }
  out[idx] = acc;
}

extern "C" void kernel_launch(void* const* d_in, const int* in_sizes, int n_in,
                              void* d_out, int out_size, void* d_ws, size_t ws_size,
                              hipStream_t stream) {
  const float* in   = (const float*)d_in[0];
  const float* w    = (const float*)d_in[1];
  const float* bias = (const float*)d_in[2];
  const int*   selh = (const int*)d_in[3];
  const int*   selw = (const int*)d_in[4];
  float* out = (float*)d_out;

  if (ws_size >= (size_t)TOTAL_WS) {
    unsigned short* wpre = (unsigned short*)d_ws;
    unsigned short* tp   = (unsigned short*)((char*)d_ws + WPRE_BYTES);
    prep<<<dim3(102, 32), dim3(256), 0, stream>>>(in, w, tp, wpre);
    sconv_mfma4<<<dim3(512), dim3(512), 0, stream>>>(tp, wpre, bias, selh, selw, out);
  } else {
    sconv_naive<<<dim3(32768), dim3(256), 0, stream>>>(in, w, bias, selh, selw, out);
  }
}